// Round 1
// baseline (713.356 us; speedup 1.0000x reference)
//
#include <hip/hip_runtime.h>
#include <math.h>

// Problem constants
#define SEQ 4096
#define DM  1024
#define NIMU 72
#define NNOISE 12
#define NJ (NIMU*NNOISE)     // 864
#define TSTEPS 300
#define PLANE (NIMU*SEQ)     // 294912 floats per noise-plane of P^T

// Workspace layout (needs (4096*1024 + 864*4096)*4 = ~31 MB):
//   xn  : 4096 x 1024 f32   (layernormed hidden states)
//   pt  : 864  x 4096 f32   (P^T: pt[j*4096 + s] = (xn @ W + b)[s, j])

__device__ __forceinline__ float softplus_f(float x) {
    // matches jax.nn.softplus = max(x,0) + log1p(exp(-|x|))
    return fmaxf(x, 0.f) + log1pf(expf(-fabsf(x)));
}

// ---------------- 1. LayerNorm ----------------
__global__ __launch_bounds__(256) void ln_kernel(const float* __restrict__ x,
                                                 const float* __restrict__ gamma,
                                                 const float* __restrict__ beta,
                                                 float* __restrict__ xn) {
    const int row = blockIdx.x;
    const int tid = threadIdx.x;
    const float4* xr = (const float4*)(x + (size_t)row * DM);
    float4 v = xr[tid];
    float s  = v.x + v.y + v.z + v.w;
    float sq = v.x*v.x + v.y*v.y + v.z*v.z + v.w*v.w;
    #pragma unroll
    for (int off = 32; off > 0; off >>= 1) {
        s  += __shfl_xor(s, off);
        sq += __shfl_xor(sq, off);
    }
    __shared__ float ls[4], lq[4];
    __shared__ float mean_s, rstd_s;
    const int wid = tid >> 6, lane = tid & 63;
    if (lane == 0) { ls[wid] = s; lq[wid] = sq; }
    __syncthreads();
    if (tid == 0) {
        float ts = ls[0] + ls[1] + ls[2] + ls[3];
        float tq = lq[0] + lq[1] + lq[2] + lq[3];
        float mean = ts * (1.f / DM);
        float var  = tq * (1.f / DM) - mean * mean;
        mean_s = mean;
        rstd_s = rsqrtf(fmaxf(var, 0.f) + 1e-5f);
    }
    __syncthreads();
    const float mean = mean_s, rstd = rstd_s;
    float4 g = ((const float4*)gamma)[tid];
    float4 b = ((const float4*)beta)[tid];
    float4 o;
    o.x = (v.x - mean) * rstd * g.x + b.x;
    o.y = (v.y - mean) * rstd * g.y + b.y;
    o.z = (v.z - mean) * rstd * g.z + b.z;
    o.w = (v.w - mean) * rstd * g.w + b.w;
    ((float4*)(xn + (size_t)row * DM))[tid] = o;
}

// ---------------- 2. GEMM: pt[j, s] = sum_k W[k, j] * xn[s, k] + b[j] ----------------
// fp32 vector-ALU GEMM (no fp32 MFMA on CDNA4). Tile: 128 s x 64 j, BK=32.
// 256 threads, micro-tile 8(s) x 4(j).
#define BS 128
#define BJ 64
#define BK 32

__global__ __launch_bounds__(256) void gemm_kernel(const float* __restrict__ xn,
                                                   const float* __restrict__ W,
                                                   const float* __restrict__ bias,
                                                   float* __restrict__ pt) {
    __shared__ float Ws[BK][BJ];        // [kk][jj] 8 KB
    __shared__ float Xs[BS][BK + 4];    // [ss][kk] pad->stride 36 floats (16B-aligned rows)
    const int tid = threadIdx.x;
    const int s0 = blockIdx.x * BS;
    const int j0 = blockIdx.y * BJ;
    const int sx = tid & 15;            // s-group: s = s0 + sx + 16*a
    const int jy = tid >> 4;            // j-group: j = j0 + 4*jy + q
    float acc[8][4];
    #pragma unroll
    for (int a = 0; a < 8; ++a)
        #pragma unroll
        for (int q = 0; q < 4; ++q) acc[a][q] = 0.f;

    for (int kt = 0; kt < DM; kt += BK) {
        #pragma unroll
        for (int i = 0; i < 8; ++i) {           // W tile: 2048 elems
            int idx = tid + 256 * i;
            int kk = idx >> 6, jj = idx & 63;
            int jg = j0 + jj;
            Ws[kk][jj] = (jg < NJ) ? W[(size_t)(kt + kk) * NJ + jg] : 0.f;
        }
        #pragma unroll
        for (int i = 0; i < 4; ++i) {           // X tile: 1024 float4
            int idx = tid + 256 * i;
            int ss = idx >> 3, kq = idx & 7;
            float4 v = *(const float4*)(xn + (size_t)(s0 + ss) * DM + kt + kq * 4);
            *(float4*)&Xs[ss][kq * 4] = v;
        }
        __syncthreads();
        #pragma unroll
        for (int g = 0; g < 8; ++g) {           // 4 k per group
            float4 wv[4];
            #pragma unroll
            for (int k2 = 0; k2 < 4; ++k2)
                wv[k2] = *(const float4*)&Ws[g * 4 + k2][jy * 4];
            #pragma unroll
            for (int a = 0; a < 8; ++a) {
                float4 xv = *(const float4*)&Xs[sx + 16 * a][g * 4];
                float xf[4] = {xv.x, xv.y, xv.z, xv.w};
                #pragma unroll
                for (int k2 = 0; k2 < 4; ++k2) {
                    acc[a][0] = fmaf(xf[k2], wv[k2].x, acc[a][0]);
                    acc[a][1] = fmaf(xf[k2], wv[k2].y, acc[a][1]);
                    acc[a][2] = fmaf(xf[k2], wv[k2].z, acc[a][2]);
                    acc[a][3] = fmaf(xf[k2], wv[k2].w, acc[a][3]);
                }
            }
        }
        __syncthreads();
    }
    #pragma unroll
    for (int q = 0; q < 4; ++q) {
        int j = j0 + jy * 4 + q;
        if (j < NJ) {
            float bj = bias[j];
            #pragma unroll
            for (int a = 0; a < 8; ++a) {
                int s = s0 + sx + 16 * a;
                pt[(size_t)j * SEQ + s] = acc[a][q] + bj;
            }
        }
    }
}

// ---------------- 3. Spring recurrence + diagonal scatter ----------------
// One thread per (imu, s). Damped sinusoid via complex rotation recurrence:
//   state_t = c*e^{i phi} * (e^{-d/2} e^{i omega})^t ; value = Im(state_t)
// Accumulate into per-block LDS window [s0, s0+256+300), flush with global fp32 atomics.
__global__ __launch_bounds__(256) void spring_kernel(const float* __restrict__ pt,
                                                     float* __restrict__ kin) {
    const int tid = threadIdx.x;
    const int s0  = blockIdx.x * 256;
    const int imu = blockIdx.y;
    const int s   = s0 + tid;
    __shared__ float win[256 + TSTEPS];
    for (int i = tid; i < 256 + TSTEPS; i += 256) win[i] = 0.f;
    __syncthreads();

    const int base = imu * SEQ + s;
    const float p0  = pt[(size_t)0 * PLANE + base];
    const float p1  = pt[(size_t)1 * PLANE + base];
    const float p2  = pt[(size_t)2 * PLANE + base];
    const float p3  = pt[(size_t)3 * PLANE + base];
    const float c1  = pt[(size_t)4 * PLANE + base];
    const float c2  = pt[(size_t)5 * PLANE + base];
    const float ph1 = pt[(size_t)6 * PLANE + base];
    const float ph2 = pt[(size_t)7 * PLANE + base];

    float dd = softplus_f(p1);
    float kk = dd * dd * 0.25f + softplus_f(p0);
    float om1 = 0.5f * sqrtf(fmaxf(4.f * kk - dd * dd, 0.f));
    float dt = softplus_f(p3);
    float kt = dt * dt * 0.25f + softplus_f(p2);
    float om2 = 0.5f * sqrtf(fmaxf(4.f * kt - dt * dt, 0.f));
    float e1 = expf(-0.5f * dd), e2 = expf(-0.5f * dt);
    float sn, cs;
    sincosf(om1, &sn, &cs); const float mr1 = e1 * cs, mi1 = e1 * sn;
    sincosf(om2, &sn, &cs); const float mr2 = e2 * cs, mi2 = e2 * sn;
    sincosf(ph1, &sn, &cs); float im1 = c1 * sn, re1 = c1 * cs;
    sincosf(ph2, &sn, &cs); float im2 = c2 * sn, re2 = c2 * cs;

    const int tmax = min(TSTEPS, SEQ - s);
    for (int t = 0; t < tmax; ++t) {
        __hip_atomic_fetch_add(&win[tid + t], im1 + im2,
                               __ATOMIC_RELAXED, __HIP_MEMORY_SCOPE_WORKGROUP);
        float r1 = fmaf(re1, mr1, -im1 * mi1);
        im1 = fmaf(re1, mi1, im1 * mr1);
        re1 = r1;
        float r2 = fmaf(re2, mr2, -im2 * mi2);
        im2 = fmaf(re2, mi2, im2 * mr2);
        re2 = r2;
    }
    __syncthreads();
    for (int i = tid; i < 256 + TSTEPS; i += 256) {
        int pos = s0 + i;
        if (pos < SEQ) {
            __hip_atomic_fetch_add(&kin[(size_t)imu * SEQ + pos], win[i],
                                   __ATOMIC_RELAXED, __HIP_MEMORY_SCOPE_AGENT);
        }
    }
}

// ---------------- 4. acc/gyro base & std outputs ----------------
__global__ __launch_bounds__(256) void tail_kernel(const float* __restrict__ pt,
                                                   float* __restrict__ out) {
    int idx = blockIdx.x * 256 + threadIdx.x;
    if (idx >= 4 * PLANE) return;
    float v = pt[(size_t)8 * PLANE + idx];   // planes 8..11 of P^T, contiguous
    int q = idx / PLANE;                     // 0:acc_base 1:acc_std 2:gyro_base 3:gyro_std
    if (q & 1) v = softplus_f(v);
    out[(size_t)PLANE + idx] = v;
}

extern "C" void kernel_launch(void* const* d_in, const int* in_sizes, int n_in,
                              void* d_out, int out_size, void* d_ws, size_t ws_size,
                              hipStream_t stream) {
    const float* hs    = (const float*)d_in[0];  // (1,4096,1024)
    const float* gamma = (const float*)d_in[1];  // (1024,)
    const float* beta  = (const float*)d_in[2];  // (1024,)
    const float* W     = (const float*)d_in[3];  // (1024,864)
    const float* b     = (const float*)d_in[4];  // (864,)
    float* out = (float*)d_out;                  // [kin | acc_b | acc_s | gyro_b | gyro_s]
    float* xn = (float*)d_ws;
    float* pt = xn + (size_t)SEQ * DM;

    // kinematics must start from zero (d_out is poisoned before every timed launch)
    hipMemsetAsync(out, 0, (size_t)PLANE * sizeof(float), stream);

    ln_kernel<<<SEQ, 256, 0, stream>>>(hs, gamma, beta, xn);
    gemm_kernel<<<dim3(SEQ / BS, (NJ + BJ - 1) / BJ), 256, 0, stream>>>(xn, W, b, pt);
    spring_kernel<<<dim3(SEQ / 256, NIMU), 256, 0, stream>>>(pt, out);
    tail_kernel<<<(4 * PLANE + 255) / 256, 256, 0, stream>>>(pt, out);
}

// Round 2
// 276.917 us; speedup vs baseline: 2.5761x; 2.5761x over previous
//
#include <hip/hip_runtime.h>
#include <math.h>

// Problem constants
#define SEQ 4096
#define DM  1024
#define NIMU 72
#define NNOISE 12
#define NJ (NIMU*NNOISE)     // 864
#define TSTEPS 300
#define PLANE (NIMU*SEQ)     // 294912 floats per noise-plane of P^T

__device__ __forceinline__ float softplus_f(float x) {
    return fmaxf(x, 0.f) + log1pf(expf(-fabsf(x)));
}

// ---------------- 1. LayerNorm ----------------
__global__ __launch_bounds__(256) void ln_kernel(const float* __restrict__ x,
                                                 const float* __restrict__ gamma,
                                                 const float* __restrict__ beta,
                                                 float* __restrict__ xn) {
    const int row = blockIdx.x;
    const int tid = threadIdx.x;
    const float4* xr = (const float4*)(x + (size_t)row * DM);
    float4 v = xr[tid];
    float s  = v.x + v.y + v.z + v.w;
    float sq = v.x*v.x + v.y*v.y + v.z*v.z + v.w*v.w;
    #pragma unroll
    for (int off = 32; off > 0; off >>= 1) {
        s  += __shfl_xor(s, off);
        sq += __shfl_xor(sq, off);
    }
    __shared__ float ls[4], lq[4];
    __shared__ float mean_s, rstd_s;
    const int wid = tid >> 6, lane = tid & 63;
    if (lane == 0) { ls[wid] = s; lq[wid] = sq; }
    __syncthreads();
    if (tid == 0) {
        float ts = ls[0] + ls[1] + ls[2] + ls[3];
        float tq = lq[0] + lq[1] + lq[2] + lq[3];
        float mean = ts * (1.f / DM);
        float var  = tq * (1.f / DM) - mean * mean;
        mean_s = mean;
        rstd_s = rsqrtf(fmaxf(var, 0.f) + 1e-5f);
    }
    __syncthreads();
    const float mean = mean_s, rstd = rstd_s;
    float4 g = ((const float4*)gamma)[tid];
    float4 b = ((const float4*)beta)[tid];
    float4 o;
    o.x = (v.x - mean) * rstd * g.x + b.x;
    o.y = (v.y - mean) * rstd * g.y + b.y;
    o.z = (v.z - mean) * rstd * g.z + b.z;
    o.w = (v.w - mean) * rstd * g.w + b.w;
    ((float4*)(xn + (size_t)row * DM))[tid] = o;
}

// ---------------- 2. GEMM: pt[j, s] = sum_k W[k, j] * xn[s, k] + b[j] ----------------
#define BS 128
#define BJ 64
#define BK 32

__global__ __launch_bounds__(256) void gemm_kernel(const float* __restrict__ xn,
                                                   const float* __restrict__ W,
                                                   const float* __restrict__ bias,
                                                   float* __restrict__ pt) {
    __shared__ float Ws[BK][BJ];
    __shared__ float Xs[BS][BK + 4];
    const int tid = threadIdx.x;
    const int s0 = blockIdx.x * BS;
    const int j0 = blockIdx.y * BJ;
    const int sx = tid & 15;
    const int jy = tid >> 4;
    float acc[8][4];
    #pragma unroll
    for (int a = 0; a < 8; ++a)
        #pragma unroll
        for (int q = 0; q < 4; ++q) acc[a][q] = 0.f;

    for (int kt = 0; kt < DM; kt += BK) {
        #pragma unroll
        for (int i = 0; i < 8; ++i) {
            int idx = tid + 256 * i;
            int kk = idx >> 6, jj = idx & 63;
            int jg = j0 + jj;
            Ws[kk][jj] = (jg < NJ) ? W[(size_t)(kt + kk) * NJ + jg] : 0.f;
        }
        #pragma unroll
        for (int i = 0; i < 4; ++i) {
            int idx = tid + 256 * i;
            int ss = idx >> 3, kq = idx & 7;
            float4 v = *(const float4*)(xn + (size_t)(s0 + ss) * DM + kt + kq * 4);
            *(float4*)&Xs[ss][kq * 4] = v;
        }
        __syncthreads();
        #pragma unroll
        for (int g = 0; g < 8; ++g) {
            float4 wv[4];
            #pragma unroll
            for (int k2 = 0; k2 < 4; ++k2)
                wv[k2] = *(const float4*)&Ws[g * 4 + k2][jy * 4];
            #pragma unroll
            for (int a = 0; a < 8; ++a) {
                float4 xv = *(const float4*)&Xs[sx + 16 * a][g * 4];
                float xf[4] = {xv.x, xv.y, xv.z, xv.w};
                #pragma unroll
                for (int k2 = 0; k2 < 4; ++k2) {
                    acc[a][0] = fmaf(xf[k2], wv[k2].x, acc[a][0]);
                    acc[a][1] = fmaf(xf[k2], wv[k2].y, acc[a][1]);
                    acc[a][2] = fmaf(xf[k2], wv[k2].z, acc[a][2]);
                    acc[a][3] = fmaf(xf[k2], wv[k2].w, acc[a][3]);
                }
            }
        }
        __syncthreads();
    }
    #pragma unroll
    for (int q = 0; q < 4; ++q) {
        int j = j0 + jy * 4 + q;
        if (j < NJ) {
            float bj = bias[j];
            #pragma unroll
            for (int a = 0; a < 8; ++a) {
                int s = s0 + sx + 16 * a;
                pt[(size_t)j * SEQ + s] = acc[a][q] + bj;
            }
        }
    }
}

// ---------------- 3. Spring recurrence + diagonal scatter ----------------
// One thread per (imu, s). Damped sinusoid via complex rotation recurrence.
// Diagonal scatter done IN REGISTERS: each lane owns 6 accumulators for output
// positions p = sbase + 64*r + lane (wave window of 384 >= 64+300). At step
// t = 64*tq + tr, dest lane gets the source value via one __shfl from lane
// (lane - tr) & 63, added into A[tq] (lane>=tr) or A[tq+1] (lane<tr).
// No LDS atomics in the loop (R1: ds_add made spring 494us @ 5% VALUBusy).
__global__ __launch_bounds__(256) void spring_kernel(const float* __restrict__ pt,
                                                     float* __restrict__ kin) {
    const int tid  = threadIdx.x;
    const int lane = tid & 63;
    const int wid  = tid >> 6;
    const int s0   = blockIdx.x * 256;
    const int imu  = blockIdx.y;
    const int sbase = s0 + (wid << 6);
    const int s    = sbase + lane;

    const int base = imu * SEQ + s;
    const float p0  = pt[(size_t)0 * PLANE + base];
    const float p1  = pt[(size_t)1 * PLANE + base];
    const float p2  = pt[(size_t)2 * PLANE + base];
    const float p3  = pt[(size_t)3 * PLANE + base];
    const float c1  = pt[(size_t)4 * PLANE + base];
    const float c2  = pt[(size_t)5 * PLANE + base];
    const float ph1 = pt[(size_t)6 * PLANE + base];
    const float ph2 = pt[(size_t)7 * PLANE + base];

    float dd = softplus_f(p1);
    float kk = dd * dd * 0.25f + softplus_f(p0);
    float om1 = 0.5f * sqrtf(fmaxf(4.f * kk - dd * dd, 0.f));
    float dt = softplus_f(p3);
    float kt = dt * dt * 0.25f + softplus_f(p2);
    float om2 = 0.5f * sqrtf(fmaxf(4.f * kt - dt * dt, 0.f));
    float e1 = expf(-0.5f * dd), e2 = expf(-0.5f * dt);
    float sn, cs;
    sincosf(om1, &sn, &cs); const float mr1 = e1 * cs, mi1 = e1 * sn;
    sincosf(om2, &sn, &cs); const float mr2 = e2 * cs, mi2 = e2 * sn;
    sincosf(ph1, &sn, &cs); float im1 = c1 * sn, re1 = c1 * cs;
    sincosf(ph2, &sn, &cs); float im2 = c2 * sn, re2 = c2 * cs;

    float A[6];
    #pragma unroll
    for (int r = 0; r < 6; ++r) A[r] = 0.f;

    // Wave-uniform trip count (keep full exec mask for the shuffle);
    // per-lane tail handled by masking val to 0.
    const int tmax_wave = min(TSTEPS, SEQ - sbase);
    const int tmax_lane = SEQ - s;   // loop already caps t < 300

    #pragma unroll
    for (int tq = 0; tq < 5; ++tq) {
        const int trmax = min(64, tmax_wave - tq * 64);
        for (int tr = 0; tr < trmax; ++tr) {
            const int t = tq * 64 + tr;
            float val = (t < tmax_lane) ? (im1 + im2) : 0.f;
            float u = __shfl(val, (lane - tr) & 63);
            A[tq]     += (lane >= tr) ? u : 0.f;
            A[tq + 1] += (lane <  tr) ? u : 0.f;
            float r1 = fmaf(re1, mr1, -im1 * mi1);
            im1 = fmaf(re1, mi1, im1 * mr1);
            re1 = r1;
            float r2 = fmaf(re2, mr2, -im2 * mi2);
            im2 = fmaf(re2, mi2, im2 * mr2);
            re2 = r2;
        }
        if (trmax < 64) break;
    }

    #pragma unroll
    for (int r = 0; r < 6; ++r) {
        int pos = sbase + 64 * r + lane;
        if (pos < SEQ) {
            __hip_atomic_fetch_add(&kin[(size_t)imu * SEQ + pos], A[r],
                                   __ATOMIC_RELAXED, __HIP_MEMORY_SCOPE_AGENT);
        }
    }
}

// ---------------- 4. acc/gyro base & std outputs ----------------
__global__ __launch_bounds__(256) void tail_kernel(const float* __restrict__ pt,
                                                   float* __restrict__ out) {
    int idx = blockIdx.x * 256 + threadIdx.x;
    if (idx >= 4 * PLANE) return;
    float v = pt[(size_t)8 * PLANE + idx];
    int q = idx / PLANE;
    if (q & 1) v = softplus_f(v);
    out[(size_t)PLANE + idx] = v;
}

extern "C" void kernel_launch(void* const* d_in, const int* in_sizes, int n_in,
                              void* d_out, int out_size, void* d_ws, size_t ws_size,
                              hipStream_t stream) {
    const float* hs    = (const float*)d_in[0];
    const float* gamma = (const float*)d_in[1];
    const float* beta  = (const float*)d_in[2];
    const float* W     = (const float*)d_in[3];
    const float* b     = (const float*)d_in[4];
    float* out = (float*)d_out;
    float* xn = (float*)d_ws;
    float* pt = xn + (size_t)SEQ * DM;

    hipMemsetAsync(out, 0, (size_t)PLANE * sizeof(float), stream);

    ln_kernel<<<SEQ, 256, 0, stream>>>(hs, gamma, beta, xn);
    gemm_kernel<<<dim3(SEQ / BS, (NJ + BJ - 1) / BJ), 256, 0, stream>>>(xn, W, b, pt);
    spring_kernel<<<dim3(SEQ / 256, NIMU), 256, 0, stream>>>(pt, out);
    tail_kernel<<<(4 * PLANE + 255) / 256, 256, 0, stream>>>(pt, out);
}